// Round 20
// baseline (155.525 us; speedup 1.0000x reference)
//
#include <hip/hip_runtime.h>
#include <hip/hip_bf16.h>

#define B_ 4
#define T_ 2048
#define E_ 1024
#define H_ 16
#define HD_ 64

typedef __attribute__((ext_vector_type(8))) short bf16x8;
typedef __attribute__((ext_vector_type(4))) float f32x4;
typedef __attribute__((ext_vector_type(16))) float f32x16;

__device__ inline ushort f2b(float f) {
  union { __hip_bfloat16 h; ushort u; } c;
  c.h = __float2bfloat16(f);
  return c.u;
}
__device__ inline short f2bs(float f) {
  union { __hip_bfloat16 h; short s; } c;
  c.h = __float2bfloat16(f);
  return c.s;
}
__device__ inline float b2f(ushort u) {
  return __uint_as_float(((unsigned)u) << 16);
}
__device__ inline int cvtpk(float lo, float hi) {
  int r;
  asm("v_cvt_pk_bf16_f32 %0, %1, %2" : "=v"(r) : "v"(lo), "v"(hi));
  return r;
}
__device__ inline f32x16 zero16() {
  f32x16 z;
#pragma unroll
  for (int i = 0; i < 16; ++i) z[i] = 0.0f;
  return z;
}

// async global->LDS, 16B per lane; lds base must be wave-uniform
__device__ inline void gload16(const ushort* gsrc, ushort* lds_uniform_base) {
  __builtin_amdgcn_global_load_lds(
      (const __attribute__((address_space(1))) void*)gsrc,
      (__attribute__((address_space(3))) void*)lds_uniform_base, 16, 0, 0);
}

// ---------------- merged weight conversion (r19) -----------------------------
__global__ __launch_bounds__(256) void cvt_kernel(const float* __restrict__ Wq,
                                                  ushort* __restrict__ Wt,
                                                  const float* __restrict__ Wp,
                                                  ushort* __restrict__ Wb) {
  int bid = blockIdx.x;
  if (bid < 768) {
    int gtid = bid * 256 + threadIdx.x;   // 0 .. 196607
    int h = gtid / (HD_ * 192);
    int rem = gtid % (HD_ * 192);
    int d = rem / 192;
    int e = rem % 192;
    int v = (e >> 6) * 64 + (e & 3) * 16 + ((e >> 2) & 15);
    Wt[h * (192 * HD_) + v * HD_ + d] = f2b(Wq[gtid]);
  } else {
    int i = ((bid - 768) * 256 + threadIdx.x) * 4;
    int n = i >> 10;                // real row (output col)
    int c = i & 1023;               // col within row (K dim)
    int vn = (n & ~63) + (n & 3) * 16 + ((n >> 2) & 15);
    float4 f = *reinterpret_cast<const float4*>(Wp + i);
    ushort4 u;
    u.x = f2b(f.x); u.y = f2b(f.y); u.z = f2b(f.z); u.w = f2b(f.w);
    *reinterpret_cast<ushort4*>(Wb + (size_t)vn * E_ + c) = u;
  }
}

// ---------------- QKV projection (r18) ---------------------------------------
__global__ __launch_bounds__(256) void qkv_kernel(const float* __restrict__ x,
                                                  const ushort* __restrict__ Wt,
                                                  const float* __restrict__ bq,
                                                  ushort* __restrict__ Q,
                                                  ushort* __restrict__ K,
                                                  ushort* __restrict__ Vt) {
  const float SCALE = (1.0f / (8.0f + 1e-5f)) * 1.4426950408889634f;
  int wave = threadIdx.x >> 6, lane = threadIdx.x & 63;
  int lo = lane & 15, hi = lane >> 4;
  int bh = blockIdx.y, b = bh >> 4, h = bh & 15;
  int t0 = blockIdx.x * 64 + wave * 16;

  const float* xr = x + (size_t)(b * T_ + t0 + lo) * E_ + h * HD_;
  bf16x8 af[2];
#pragma unroll
  for (int c = 0; c < 2; ++c) {
    float4 f0 = *reinterpret_cast<const float4*>(xr + c * 32 + hi * 8);
    float4 f1 = *reinterpret_cast<const float4*>(xr + c * 32 + hi * 8 + 4);
    bf16x8 v;
    v[0] = f2bs(f0.x); v[1] = f2bs(f0.y); v[2] = f2bs(f0.z); v[3] = f2bs(f0.w);
    v[4] = f2bs(f1.x); v[5] = f2bs(f1.y); v[6] = f2bs(f1.z); v[7] = f2bs(f1.w);
    af[c] = v;
  }

  const ushort* Wh = Wt + h * (192 * HD_);
#pragma unroll
  for (int g = 0; g < 3; ++g) {          // 0=Q, 1=K, 2=V
    f32x4 accg[4];
#pragma unroll
    for (int j = 0; j < 4; ++j) {
      int n0 = (g * 4 + j) * 16;
      bf16x8 bf0 = *reinterpret_cast<const bf16x8*>(Wh + (size_t)(n0 + lo) * HD_ + hi * 8);
      bf16x8 bf1 = *reinterpret_cast<const bf16x8*>(Wh + (size_t)(n0 + lo) * HD_ + 32 + hi * 8);
      f32x4 acc = {0.0f, 0.0f, 0.0f, 0.0f};
      acc = __builtin_amdgcn_mfma_f32_16x16x32_bf16(af[0], bf0, acc, 0, 0, 0);
      acc = __builtin_amdgcn_mfma_f32_16x16x32_bf16(af[1], bf1, acc, 0, 0, 0);
      accg[j] = acc;
    }
    float4 bq4 = *reinterpret_cast<const float4*>(bq + h * 192 + g * 64 + 4 * lo);
    if (g < 2) {
      ushort* dst = (g == 0) ? Q : K;
      float sc = (g == 0) ? SCALE : 1.0f;
#pragma unroll
      for (int r = 0; r < 4; ++r) {
        int t = t0 + hi * 4 + r;
        ushort4 u;
        u.x = f2b((accg[0][r] + bq4.x) * sc);
        u.y = f2b((accg[1][r] + bq4.y) * sc);
        u.z = f2b((accg[2][r] + bq4.z) * sc);
        u.w = f2b((accg[3][r] + bq4.w) * sc);
        *reinterpret_cast<ushort4*>(dst + ((size_t)bh * T_ + t) * HD_ + 4 * lo) = u;
      }
    } else {
      float bj[4] = {bq4.x, bq4.y, bq4.z, bq4.w};
#pragma unroll
      for (int j = 0; j < 4; ++j) {
        int hd = 4 * lo + j;
        ushort4 u;
        u.x = f2b(accg[j][0] + bj[j]);
        u.y = f2b(accg[j][1] + bj[j]);
        u.z = f2b(accg[j][2] + bj[j]);
        u.w = f2b(accg[j][3] + bj[j]);
        int col = t0 + hi * 4 + hd * 8;
        col &= (T_ - 1);
        *reinterpret_cast<ushort4*>(Vt + ((size_t)bh * HD_ + hd) * T_ + col) = u;
      }
    }
  }
}

// ====================== shared attention tile machinery ======================
// (swapped-operand 32x32; identical math to r15, verified)
#define ATTN_PREAMBLE()                                                         \
  int wave = threadIdx.x >> 6, lane = threadIdx.x & 63;                         \
  int q5 = lane & 31, hi5 = lane >> 5;                                          \
  int bh = blockIdx.x, b = bh >> 4, h = bh & 15;                                \
  const ushort* Kbh = K + (size_t)bh * T_ * HD_;                                \
  const ushort* Vbh = Vt + (size_t)bh * HD_ * T_;                               \
  int srow = lane >> 3;                                                         \
  int sch = lane & 7;

#define ATTN_STAGE_BODY(BUF, KT_)                                               \
  {                                                                             \
    int row = wave * 8 + srow;                                                  \
    const ushort* gk = Kbh + (size_t)((KT_) + row) * HD_ + ((sch ^ (row & 7)) * 8); \
    gload16(gk, &Ks[BUF][(wave * 8) * 64]);                                     \
    int col = ((KT_) + ((sch ^ (row & 7)) + row) * 8) & (T_ - 1);               \
    const ushort* gv = Vbh + (size_t)row * T_ + col;                            \
    gload16(gv, &Vs[BUF][(wave * 8) * 64]);                                     \
  }

// ---------------- split-K flash attention (main pass) ------------------------
// grid (bh=64, y=16): y2=y>>1 -> qt (heavy-first pairing), half=y&1.
// Block processes tiles {half, half+2, ...} (2qt+2 of them). Writes
// UNNORMALIZED partial O (bf16) + per-row (m,l) to mlf. Same 8-wave, 4-buf
// pair-wise pipeline as r15.
__global__ __launch_bounds__(512) void attn_split_kernel(const ushort* __restrict__ Q,
                                                         const ushort* __restrict__ K,
                                                         const ushort* __restrict__ Vt,
                                                         ushort* __restrict__ O0,
                                                         ushort* __restrict__ O1,
                                                         float* __restrict__ mlf) {
  __shared__ ushort Ks[4][64 * 64];
  __shared__ ushort Vs[4][64 * 64];

  ATTN_PREAMBLE();
  int y = blockIdx.y;
  int y2 = y >> 1, half = y & 1;
  int qt = (y2 < 4) ? (7 - y2) : (y2 - 4);
  int qw = qt * 256 + wave * 32;

  bf16x8 qf[4];
#pragma unroll
  for (int ks = 0; ks < 4; ++ks)
    qf[ks] = *reinterpret_cast<const bf16x8*>(
        Q + ((size_t)bh * T_ + qw + q5) * HD_ + ks * 16 + hi5 * 8);

  f32x16 ot[2];
  ot[0] = zero16(); ot[1] = zero16();
  float mreg = -1e30f, lreg = 0.0f;

  int nlist = 2 * qt + 2;   // even, >= 2

#define SSTAGE(BUF, LI)  { int kt_ = (half + 2 * (LI)) << 6; ATTN_STAGE_BODY(BUF, kt_) }

  auto compute_tile = [&](int li, int buf) {
    int kt = (half + 2 * li) << 6;
    if (kt > qw + 31) return;
    f32x16 s[2];
#pragma unroll
    for (int g = 0; g < 2; ++g) {
      int krow = g * 32 + q5;
      bf16x8 kf[4];
#pragma unroll
      for (int ks = 0; ks < 4; ++ks)
        kf[ks] = *reinterpret_cast<const bf16x8*>(
            &Ks[buf][krow * 64 + (((2 * ks + hi5) ^ (krow & 7)) * 8)]);
      f32x16 acc = zero16();
      __builtin_amdgcn_s_setprio(1);
#pragma unroll
      for (int ks = 0; ks < 4; ++ks)
        acc = __builtin_amdgcn_mfma_f32_32x32x16_bf16(kf[ks], qf[ks], acc, 0, 0, 0);
      __builtin_amdgcn_s_setprio(0);
      s[g] = acc;
    }
    if (kt + 63 > qw) {
      int q = qw + q5;
#pragma unroll
      for (int g = 0; g < 2; ++g)
#pragma unroll
        for (int r = 0; r < 16; ++r) {
          int key = kt + g * 32 + (r & 3) + 8 * (r >> 2) + 4 * hi5;
          if (key > q) s[g][r] = -1e30f;
        }
    }
    float t8[8];
#pragma unroll
    for (int i = 0; i < 8; ++i)
      t8[i] = fmaxf(fmaxf(s[0][i], s[0][i + 8]), fmaxf(s[1][i], s[1][i + 8]));
    float mx = fmaxf(fmaxf(fmaxf(t8[0], t8[1]), fmaxf(t8[2], t8[3])),
                     fmaxf(fmaxf(t8[4], t8[5]), fmaxf(t8[6], t8[7])));
    mx = fmaxf(mx, __shfl_xor(mx, 32));
    float nm = fmaxf(mreg, mx);
    float alpha = exp2f(mreg - nm);
    mreg = nm;
#pragma unroll
    for (int g = 0; g < 2; ++g)
#pragma unroll
      for (int r = 0; r < 16; ++r)
        s[g][r] = exp2f(s[g][r] - nm);
    float u8[8];
#pragma unroll
    for (int i = 0; i < 8; ++i)
      u8[i] = (s[0][i] + s[0][i + 8]) + (s[1][i] + s[1][i + 8]);
    float rs = ((u8[0] + u8[1]) + (u8[2] + u8[3])) + ((u8[4] + u8[5]) + (u8[6] + u8[7]));
    rs += __shfl_xor(rs, 32);
    lreg = lreg * alpha + rs;
#pragma unroll
    for (int nh = 0; nh < 2; ++nh)
#pragma unroll
      for (int r = 0; r < 16; ++r) ot[nh][r] *= alpha;

    bf16x8 pb4[4];
#pragma unroll
    for (int ks = 0; ks < 4; ++ks) {
      int g = ks >> 1;
      int R0 = 2 * (ks & 1), R1 = R0 + 1;
      int a0w0 = cvtpk(s[g][4 * R0 + 0], s[g][4 * R0 + 1]);
      int a0w1 = cvtpk(s[g][4 * R0 + 2], s[g][4 * R0 + 3]);
      int a1w0 = cvtpk(s[g][4 * R1 + 0], s[g][4 * R1 + 1]);
      int a1w1 = cvtpk(s[g][4 * R1 + 2], s[g][4 * R1 + 3]);
      int pA0w0 = __shfl_xor(a0w0, 32);
      int pA0w1 = __shfl_xor(a0w1, 32);
      int pA1w0 = __shfl_xor(a1w0, 32);
      int pA1w1 = __shfl_xor(a1w1, 32);
      int4 w;
      w.x = hi5 ? pA1w0 : a0w0;
      w.y = hi5 ? pA1w1 : a0w1;
      w.z = hi5 ? a1w0 : pA0w0;
      w.w = hi5 ? a1w1 : pA0w1;
      pb4[ks] = *reinterpret_cast<bf16x8*>(&w);
    }
#pragma unroll
    for (int nh = 0; nh < 2; ++nh) {
      int vrow = nh * 32 + q5;
      bf16x8 vf[4];
#pragma unroll
      for (int ks = 0; ks < 4; ++ks)
        vf[ks] = *reinterpret_cast<const bf16x8*>(
            &Vs[buf][vrow * 64 + (((2 * ks + hi5) ^ (vrow & 7)) * 8)]);
      __builtin_amdgcn_s_setprio(1);
#pragma unroll
      for (int ks = 0; ks < 4; ++ks)
        ot[nh] = __builtin_amdgcn_mfma_f32_32x32x16_bf16(vf[ks], pb4[ks], ot[nh], 0, 0, 0);
      __builtin_amdgcn_s_setprio(0);
    }
  };

  SSTAGE(0, 0);
  SSTAGE(1, 1);

  int npairs = nlist >> 1;
  for (int p = 0; p < npairs; ++p) {
    int l0 = 2 * p, l1 = 2 * p + 1;
    asm volatile("s_waitcnt vmcnt(0)" ::: "memory");
    __builtin_amdgcn_s_barrier();
    {
      int pr0 = l0 + 2, pr1 = l0 + 3;
      int s0 = (pr0 < nlist) ? pr0 : 0;
      int s1 = (pr1 < nlist) ? pr1 : 0;
      SSTAGE(pr0 & 3, s0);
      SSTAGE(pr1 & 3, s1);
    }
    compute_tile(l0, l0 & 3);
    compute_tile(l1, l1 & 3);
  }
#undef SSTAGE

  // epilogue: store UNNORMALIZED partial O + (m,l)
  ushort* Opart = half ? O1 : O0;
  int t = qw + q5;
  ushort* aop = Opart + ((size_t)(b * T_ + t) * H_ + h) * HD_;
#pragma unroll
  for (int nh = 0; nh < 2; ++nh)
#pragma unroll
    for (int R = 0; R < 4; ++R) {
      ushort4 u;
      u.x = f2b(ot[nh][4 * R + 0]);
      u.y = f2b(ot[nh][4 * R + 1]);
      u.z = f2b(ot[nh][4 * R + 2]);
      u.w = f2b(ot[nh][4 * R + 3]);
      *reinterpret_cast<ushort4*>(aop + nh * 32 + 8 * R + 4 * hi5) = u;
    }
  if (hi5 == 0) {
    size_t mlrow = (size_t)bh * T_ + qw + q5;
    float2 v = {mreg, lreg};
    *reinterpret_cast<float2*>(mlf + ((size_t)half * (B_ * H_ * T_) + mlrow) * 2) = v;
  }
}

// ---------------- split-K combine --------------------------------------------
// gid -> row = (b*T+t)*H + h (8 hd-chunks per row). AO = (O0*w0 + O1*w1)/l.
__global__ __launch_bounds__(256) void combine_kernel(const ushort* __restrict__ O0,
                                                      const ushort* __restrict__ O1,
                                                      const float* __restrict__ mlf,
                                                      ushort* __restrict__ AO) {
  int gid = blockIdx.x * 256 + threadIdx.x;
  int row = gid >> 3;
  int c8 = (gid & 7) * 8;
  int h = row & 15;
  int bt = row >> 4;             // b*T + t
  int t = bt & (T_ - 1);
  int b = bt >> 11;
  size_t mlrow = ((size_t)(b * H_ + h) * T_ + t);
  float2 ml0 = *reinterpret_cast<const float2*>(mlf + mlrow * 2);
  float2 ml1 = *reinterpret_cast<const float2*>(mlf + ((size_t)(B_ * H_ * T_) + mlrow) * 2);
  float m = fmaxf(ml0.x, ml1.x);
  float w0 = exp2f(ml0.x - m), w1 = exp2f(ml1.x - m);
  float inv = 1.0f / (ml0.y * w0 + ml1.y * w1);
  const bf16x8 a = *reinterpret_cast<const bf16x8*>(O0 + (size_t)row * HD_ + c8);
  const bf16x8 c = *reinterpret_cast<const bf16x8*>(O1 + (size_t)row * HD_ + c8);
  bf16x8 o;
#pragma unroll
  for (int j = 0; j < 8; ++j)
    o[j] = f2bs((b2f((ushort)a[j]) * w0 + b2f((ushort)c[j]) * w1) * inv);
  *reinterpret_cast<bf16x8*>(AO + (size_t)row * HD_ + c8) = o;
}

// ---------------- single-pass attention (r15, fallback if ws too small) ------
__global__ __launch_bounds__(512) void attn_kernel(const ushort* __restrict__ Q,
                                                   const ushort* __restrict__ K,
                                                   const ushort* __restrict__ Vt,
                                                   ushort* __restrict__ AO) {
  __shared__ ushort Ks[4][64 * 64];
  __shared__ ushort Vs[4][64 * 64];

  ATTN_PREAMBLE();
  int y = blockIdx.y;
  int qt = (y < 4) ? (7 - y) : (y - 4);
  int qw = qt * 256 + wave * 32;

  bf16x8 qf[4];
#pragma unroll
  for (int ks = 0; ks < 4; ++ks)
    qf[ks] = *reinterpret_cast<const bf16x8*>(
        Q + ((size_t)bh * T_ + qw + q5) * HD_ + ks * 16 + hi5 * 8);

  f32x16 ot[2];
  ot[0] = zero16(); ot[1] = zero16();
  float mreg = -1e30f, lreg = 0.0f;

  int ntiles = qt * 4 + 4;

#define FSTAGE(BUF, TILE)  { int kt_ = (TILE) << 6; ATTN_STAGE_BODY(BUF, kt_) }

  auto compute_tile = [&](int tile, int buf) {
    int kt = tile << 6;
    if (kt > qw + 31) return;
    f32x16 s[2];
#pragma unroll
    for (int g = 0; g < 2; ++g) {
      int krow = g * 32 + q5;
      bf16x8 kf[4];
#pragma unroll
      for (int ks = 0; ks < 4; ++ks)
        kf[ks] = *reinterpret_cast<const bf16x8*>(
            &Ks[buf][krow * 64 + (((2 * ks + hi5) ^ (krow & 7)) * 8)]);
      f32x16 acc = zero16();
      __builtin_amdgcn_s_setprio(1);
#pragma unroll
      for (int ks = 0; ks < 4; ++ks)
        acc = __builtin_amdgcn_mfma_f32_32x32x16_bf16(kf[ks], qf[ks], acc, 0, 0, 0);
      __builtin_amdgcn_s_setprio(0);
      s[g] = acc;
    }
    if (kt + 63 > qw) {
      int q = qw + q5;
#pragma unroll
      for (int g = 0; g < 2; ++g)
#pragma unroll
        for (int r = 0; r < 16; ++r) {
          int key = kt + g * 32 + (r & 3) + 8 * (r >> 2) + 4 * hi5;
          if (key > q) s[g][r] = -1e30f;
        }
    }
    float t8[8];
#pragma unroll
    for (int i = 0; i < 8; ++i)
      t8[i] = fmaxf(fmaxf(s[0][i], s[0][i + 8]), fmaxf(s[1][i], s[1][i + 8]));
    float mx = fmaxf(fmaxf(fmaxf(t8[0], t8[1]), fmaxf(t8[2], t8[3])),
                     fmaxf(fmaxf(t8[4], t8[5]), fmaxf(t8[6], t8[7])));
    mx = fmaxf(mx, __shfl_xor(mx, 32));
    float nm = fmaxf(mreg, mx);
    float alpha = exp2f(mreg - nm);
    mreg = nm;
#pragma unroll
    for (int g = 0; g < 2; ++g)
#pragma unroll
      for (int r = 0; r < 16; ++r)
        s[g][r] = exp2f(s[g][r] - nm);
    float u8[8];
#pragma unroll
    for (int i = 0; i < 8; ++i)
      u8[i] = (s[0][i] + s[0][i + 8]) + (s[1][i] + s[1][i + 8]);
    float rs = ((u8[0] + u8[1]) + (u8[2] + u8[3])) + ((u8[4] + u8[5]) + (u8[6] + u8[7]));
    rs += __shfl_xor(rs, 32);
    lreg = lreg * alpha + rs;
#pragma unroll
    for (int nh = 0; nh < 2; ++nh)
#pragma unroll
      for (int r = 0; r < 16; ++r) ot[nh][r] *= alpha;

    bf16x8 pb4[4];
#pragma unroll
    for (int ks = 0; ks < 4; ++ks) {
      int g = ks >> 1;
      int R0 = 2 * (ks & 1), R1 = R0 + 1;
      int a0w0 = cvtpk(s[g][4 * R0 + 0], s[g][4 * R0 + 1]);
      int a0w1 = cvtpk(s[g][4 * R0 + 2], s[g][4 * R0 + 3]);
      int a1w0 = cvtpk(s[g][4 * R1 + 0], s[g][4 * R1 + 1]);
      int a1w1 = cvtpk(s[g][4 * R1 + 2], s[g][4 * R1 + 3]);
      int pA0w0 = __shfl_xor(a0w0, 32);
      int pA0w1 = __shfl_xor(a0w1, 32);
      int pA1w0 = __shfl_xor(a1w0, 32);
      int pA1w1 = __shfl_xor(a1w1, 32);
      int4 w;
      w.x = hi5 ? pA1w0 : a0w0;
      w.y = hi5 ? pA1w1 : a0w1;
      w.z = hi5 ? a1w0 : pA0w0;
      w.w = hi5 ? a1w1 : pA0w1;
      pb4[ks] = *reinterpret_cast<bf16x8*>(&w);
    }
#pragma unroll
    for (int nh = 0; nh < 2; ++nh) {
      int vrow = nh * 32 + q5;
      bf16x8 vf[4];
#pragma unroll
      for (int ks = 0; ks < 4; ++ks)
        vf[ks] = *reinterpret_cast<const bf16x8*>(
            &Vs[buf][vrow * 64 + (((2 * ks + hi5) ^ (vrow & 7)) * 8)]);
      __builtin_amdgcn_s_setprio(1);
#pragma unroll
      for (int ks = 0; ks < 4; ++ks)
        ot[nh] = __builtin_amdgcn_mfma_f32_32x32x16_bf16(vf[ks], pb4[ks], ot[nh], 0, 0, 0);
      __builtin_amdgcn_s_setprio(0);
    }
  };

  FSTAGE(0, 0);
  FSTAGE(1, 1);

  int npairs = ntiles >> 1;
  for (int p = 0; p < npairs; ++p) {
    int t0 = 2 * p, t1 = 2 * p + 1;
    asm volatile("s_waitcnt vmcnt(0)" ::: "memory");
    __builtin_amdgcn_s_barrier();
    {
      int pr0 = t0 + 2, pr1 = t0 + 3;
      int s0 = (pr0 < ntiles) ? pr0 : 0;
      int s1 = (pr1 < ntiles) ? pr1 : 0;
      FSTAGE(pr0 & 3, s0);
      FSTAGE(pr1 & 3, s1);
    }
    compute_tile(t0, t0 & 3);
    compute_tile(t1, t1 & 3);
  }
#undef FSTAGE

  float inv = 1.0f / lreg;
  int t = qw + q5;
  ushort* aop = AO + ((size_t)(b * T_ + t) * H_ + h) * HD_;
#pragma unroll
  for (int nh = 0; nh < 2; ++nh)
#pragma unroll
    for (int R = 0; R < 4; ++R) {
      ushort4 u;
      u.x = f2b(ot[nh][4 * R + 0] * inv);
      u.y = f2b(ot[nh][4 * R + 1] * inv);
      u.z = f2b(ot[nh][4 * R + 2] * inv);
      u.w = f2b(ot[nh][4 * R + 3] * inv);
      *reinterpret_cast<ushort4*>(aop + nh * 32 + 8 * R + 4 * hi5) = u;
    }
}

// ---------------- Output projection (r19) ------------------------------------
__global__ __launch_bounds__(256) void proj_kernel(const ushort* __restrict__ A,
                                                   const ushort* __restrict__ Wb,
                                                   const float* __restrict__ bias,
                                                   float* __restrict__ out) {
  __shared__ ushort As[2][128 * 32];
  __shared__ ushort Bs[2][128 * 32];
  int tid = threadIdx.x;
  int wave = tid >> 6, lane = tid & 63;
  int lo = lane & 15, hi = lane >> 4;
  int wr = wave >> 1, wc = wave & 1;
  int m0 = blockIdx.y * 128, n0 = blockIdx.x * 128;

  int srow4 = lane >> 2;
  int sch4 = lane & 3;
  int swz = sch4 ^ ((srow4 >> 1) & 3);

#define PSTAGE(BUF, K0)                                                          \
  {                                                                              \
    _Pragma("unroll")                                                            \
    for (int rep = 0; rep < 2; ++rep) {                                          \
      int row = wave * 32 + rep * 16 + srow4;                                    \
      gload16(A + (size_t)(m0 + row) * E_ + (K0) + swz * 8,                      \
              &As[BUF][(wave * 32 + rep * 16) * 32]);                            \
      gload16(Wb + (size_t)(n0 + row) * E_ + (K0) + swz * 8,                     \
              &Bs[BUF][(wave * 32 + rep * 16) * 32]);                            \
    }                                                                            \
  }

  f32x4 acc[4][4] = {};
  PSTAGE(0, 0);
  asm volatile("s_waitcnt vmcnt(0)" ::: "memory");
  __syncthreads();

  int cur = 0;
  for (int k0 = 0; k0 < E_; k0 += 32) {
    int kpre = (k0 + 32) & (E_ - 1);
    PSTAGE(cur ^ 1, kpre);
    bf16x8 af[4], bfr[4];
#pragma unroll
    for (int i = 0; i < 4; ++i) {
      int row = wr * 64 + i * 16 + lo;
      af[i] = *reinterpret_cast<const bf16x8*>(
          &As[cur][row * 32 + ((hi ^ ((row >> 1) & 3)) * 8)]);
    }
#pragma unroll
    for (int j = 0; j < 4; ++j) {
      int row = wc * 64 + j * 16 + lo;
      bfr[j] = *reinterpret_cast<const bf16x8*>(
          &Bs[cur][row * 32 + ((hi ^ ((row >> 1) & 3)) * 8)]);
    }
    __builtin_amdgcn_s_setprio(1);
#pragma unroll
    for (int i = 0; i < 4; ++i)
#pragma unroll
      for (int j = 0; j < 4; ++j)
        acc[i][j] = __builtin_amdgcn_mfma_f32_16x16x32_bf16(af[i], bfr[j], acc[i][j], 0, 0, 0);
    __builtin_amdgcn_s_setprio(0);
    asm volatile("s_waitcnt vmcnt(0)" ::: "memory");
    __syncthreads();
    cur ^= 1;
  }
#undef PSTAGE

  float4 b4 = *reinterpret_cast<const float4*>(bias + n0 + wc * 64 + 4 * lo);
#pragma unroll
  for (int i = 0; i < 4; ++i)
#pragma unroll
    for (int r = 0; r < 4; ++r) {
      int mm = m0 + wr * 64 + i * 16 + hi * 4 + r;
      float4 u;
      u.x = acc[i][0][r] + b4.x;
      u.y = acc[i][1][r] + b4.y;
      u.z = acc[i][2][r] + b4.z;
      u.w = acc[i][3][r] + b4.w;
      *reinterpret_cast<float4*>(out + (size_t)mm * E_ + n0 + wc * 64 + 4 * lo) = u;
    }
}

extern "C" void kernel_launch(void* const* d_in, const int* in_sizes, int n_in,
                              void* d_out, int out_size, void* d_ws, size_t ws_size,
                              hipStream_t stream) {
  (void)in_sizes; (void)n_in; (void)out_size;
  const float* x  = (const float*)d_in[0];
  const float* Wq = (const float*)d_in[1];
  const float* bq = (const float*)d_in[2];
  const float* Wp = (const float*)d_in[3];
  const float* bp = (const float*)d_in[4];
  float* out = (float*)d_out;

  const size_t NQ = (size_t)B_ * H_ * T_ * HD_;   // 8,388,608 ushorts
  const size_t WBN = (size_t)E_ * E_;
  const size_t WTN = (size_t)H_ * 192 * HD_;
  const size_t MLN = (size_t)2 * B_ * H_ * T_ * 2;   // floats
  // split layout: Q | K | Vt | O0 | O1 | Wb | Wt | ml(float)
  size_t need_split = (5 * NQ + WBN + WTN) * 2 + MLN * 4;

  ushort* ws = (ushort*)d_ws;
  ushort* Q  = ws;
  ushort* K  = ws + NQ;
  ushort* Vt = ws + 2 * NQ;
  ushort* O0 = ws + 3 * NQ;

  if (ws_size >= need_split) {
    ushort* O1 = ws + 4 * NQ;
    ushort* Wb = ws + 5 * NQ;
    ushort* Wt = ws + 5 * NQ + WBN;
    float* mlf = (float*)(ws + 5 * NQ + WBN + WTN);

    cvt_kernel<<<dim3(1792), dim3(256), 0, stream>>>(Wq, Wt, Wp, Wb);
    qkv_kernel<<<dim3(T_ / 64, B_ * H_), dim3(256), 0, stream>>>(x, Wt, bq, Q, K, Vt);
    attn_split_kernel<<<dim3(B_ * H_, 16), dim3(512), 0, stream>>>(Q, K, Vt, O0, O1, mlf);
    // combine writes final AO into Q's slot (Q dead after attn)
    combine_kernel<<<dim3((B_ * T_ * H_ * 8) / 256), dim3(256), 0, stream>>>(O0, O1, mlf, Q);
    proj_kernel<<<dim3(E_ / 128, (B_ * T_) / 128), dim3(256), 0, stream>>>(Q, Wb, bp, out);
  } else {
    // fallback: single-pass attn (r15 layout)
    ushort* AO = ws + 3 * NQ;
    ushort* Wb = ws + 4 * NQ;
    ushort* Wt = ws + 4 * NQ + WBN;

    cvt_kernel<<<dim3(1792), dim3(256), 0, stream>>>(Wq, Wt, Wp, Wb);
    qkv_kernel<<<dim3(T_ / 64, B_ * H_), dim3(256), 0, stream>>>(x, Wt, bq, Q, K, Vt);
    attn_kernel<<<dim3(B_ * H_, 8), dim3(512), 0, stream>>>(Q, K, Vt, AO);
    proj_kernel<<<dim3(E_ / 128, (B_ * T_) / 128), dim3(256), 0, stream>>>(AO, Wb, bp, out);
  }
}

// Round 21
// 145.141 us; speedup vs baseline: 1.0715x; 1.0715x over previous
//
#include <hip/hip_runtime.h>
#include <hip/hip_bf16.h>

#define B_ 4
#define T_ 2048
#define E_ 1024
#define H_ 16
#define HD_ 64

typedef __attribute__((ext_vector_type(8))) short bf16x8;
typedef __attribute__((ext_vector_type(4))) float f32x4;
typedef __attribute__((ext_vector_type(16))) float f32x16;

__device__ inline ushort f2b(float f) {
  union { __hip_bfloat16 h; ushort u; } c;
  c.h = __float2bfloat16(f);
  return c.u;
}
__device__ inline short f2bs(float f) {
  union { __hip_bfloat16 h; short s; } c;
  c.h = __float2bfloat16(f);
  return c.s;
}
__device__ inline int cvtpk(float lo, float hi) {
  int r;
  asm("v_cvt_pk_bf16_f32 %0, %1, %2" : "=v"(r) : "v"(lo), "v"(hi));
  return r;
}
__device__ inline f32x16 zero16() {
  f32x16 z;
#pragma unroll
  for (int i = 0; i < 16; ++i) z[i] = 0.0f;
  return z;
}

// async global->LDS, 16B per lane; lds base must be wave-uniform
__device__ inline void gload16(const ushort* gsrc, ushort* lds_uniform_base) {
  __builtin_amdgcn_global_load_lds(
      (const __attribute__((address_space(1))) void*)gsrc,
      (__attribute__((address_space(3))) void*)lds_uniform_base, 16, 0, 0);
}

// ---------------- merged weight conversion ----------------------------------
// blocks 0..767:   W_qkv fp32 [H][HD][192] -> bf16 Wt [H][192v][HD], rows
//                  PERMUTED: real col e at virtual row
//                  v(e) = (e>>6)*64 + (e&3)*16 + ((e>>2)&15)  — so MFMA lane
//                  lo's 4 group-g tiles hold real cols {4lo..4lo+3} contiguous.
// blocks 768..1791: W_proj fp32 [E][E] -> bf16 Wb [E][E]
__global__ __launch_bounds__(256) void cvt_kernel(const float* __restrict__ Wq,
                                                  ushort* __restrict__ Wt,
                                                  const float* __restrict__ Wp,
                                                  ushort* __restrict__ Wb) {
  int bid = blockIdx.x;
  if (bid < 768) {
    int gtid = bid * 256 + threadIdx.x;   // 0 .. 196607
    int h = gtid / (HD_ * 192);
    int rem = gtid % (HD_ * 192);
    int d = rem / 192;
    int e = rem % 192;
    int v = (e >> 6) * 64 + (e & 3) * 16 + ((e >> 2) & 15);
    Wt[h * (192 * HD_) + v * HD_ + d] = f2b(Wq[gtid]);
  } else {
    int i = ((bid - 768) * 256 + threadIdx.x) * 4;
    float4 f = *reinterpret_cast<const float4*>(Wp + i);
    ushort4 u;
    u.x = f2b(f.x); u.y = f2b(f.y); u.z = f2b(f.z); u.w = f2b(f.w);
    *reinterpret_cast<ushort4*>(Wb + i) = u;
  }
}

// ---------------- QKV projection (r18) -------------------------
// Q,K written [B,H,T,HD] via coalesced ushort4 stores (Wt row permutation);
// V transposed+rotated: (hd,t) at Vt[bh][hd][(t+hd*8)%T_].
// Q pre-scaled by (1/(8+1e-5)) * log2(e).
__global__ __launch_bounds__(256) void qkv_kernel(const float* __restrict__ x,
                                                  const ushort* __restrict__ Wt,
                                                  const float* __restrict__ bq,
                                                  ushort* __restrict__ Q,
                                                  ushort* __restrict__ K,
                                                  ushort* __restrict__ Vt) {
  const float SCALE = (1.0f / (8.0f + 1e-5f)) * 1.4426950408889634f;
  int wave = threadIdx.x >> 6, lane = threadIdx.x & 63;
  int lo = lane & 15, hi = lane >> 4;
  int bh = blockIdx.y, b = bh >> 4, h = bh & 15;
  int t0 = blockIdx.x * 64 + wave * 16;

  const float* xr = x + (size_t)(b * T_ + t0 + lo) * E_ + h * HD_;
  bf16x8 af[2];
#pragma unroll
  for (int c = 0; c < 2; ++c) {
    float4 f0 = *reinterpret_cast<const float4*>(xr + c * 32 + hi * 8);
    float4 f1 = *reinterpret_cast<const float4*>(xr + c * 32 + hi * 8 + 4);
    bf16x8 v;
    v[0] = f2bs(f0.x); v[1] = f2bs(f0.y); v[2] = f2bs(f0.z); v[3] = f2bs(f0.w);
    v[4] = f2bs(f1.x); v[5] = f2bs(f1.y); v[6] = f2bs(f1.z); v[7] = f2bs(f1.w);
    af[c] = v;
  }

  const ushort* Wh = Wt + h * (192 * HD_);
#pragma unroll
  for (int g = 0; g < 3; ++g) {          // 0=Q, 1=K, 2=V
    f32x4 accg[4];
#pragma unroll
    for (int j = 0; j < 4; ++j) {
      int n0 = (g * 4 + j) * 16;
      bf16x8 bf0 = *reinterpret_cast<const bf16x8*>(Wh + (size_t)(n0 + lo) * HD_ + hi * 8);
      bf16x8 bf1 = *reinterpret_cast<const bf16x8*>(Wh + (size_t)(n0 + lo) * HD_ + 32 + hi * 8);
      f32x4 acc = {0.0f, 0.0f, 0.0f, 0.0f};
      acc = __builtin_amdgcn_mfma_f32_16x16x32_bf16(af[0], bf0, acc, 0, 0, 0);
      acc = __builtin_amdgcn_mfma_f32_16x16x32_bf16(af[1], bf1, acc, 0, 0, 0);
      accg[j] = acc;
    }
    // bias for real cols g*64 + 4lo .. +3 (aligned float4)
    float4 bq4 = *reinterpret_cast<const float4*>(bq + h * 192 + g * 64 + 4 * lo);
    if (g < 2) {
      ushort* dst = (g == 0) ? Q : K;
      float sc = (g == 0) ? SCALE : 1.0f;
#pragma unroll
      for (int r = 0; r < 4; ++r) {
        int t = t0 + hi * 4 + r;
        ushort4 u;
        u.x = f2b((accg[0][r] + bq4.x) * sc);
        u.y = f2b((accg[1][r] + bq4.y) * sc);
        u.z = f2b((accg[2][r] + bq4.z) * sc);
        u.w = f2b((accg[3][r] + bq4.w) * sc);
        *reinterpret_cast<ushort4*>(dst + ((size_t)bh * T_ + t) * HD_ + 4 * lo) = u;
      }
    } else {
      float bj[4] = {bq4.x, bq4.y, bq4.z, bq4.w};
#pragma unroll
      for (int j = 0; j < 4; ++j) {
        int hd = 4 * lo + j;
        ushort4 u;
        u.x = f2b(accg[j][0] + bj[j]);
        u.y = f2b(accg[j][1] + bj[j]);
        u.z = f2b(accg[j][2] + bj[j]);
        u.w = f2b(accg[j][3] + bj[j]);
        int col = t0 + hi * 4 + hd * 8;
        col &= (T_ - 1);
        *reinterpret_cast<ushort4*>(Vt + ((size_t)bh * HD_ + hd) * T_ + col) = u;
      }
    }
  }
}

// ---------------- Flash attention (causal), swapped-operand 32x32 (r15) -----
// grid (bh=64, y=8). 512 thr = 8 waves, 32 q-rows each (256-row strips);
// qt order [7,6,5,4,0,1,2,3]. 4-buffer PAIR-WISE pipeline: per 2 tiles, one
// {vmcnt(0) [waits loads issued a full pair ago ~free]; s_barrier;
//  STAGE(2p+2),STAGE(2p+3) [post-barrier, race-free]; compute(2p); compute(2p+1)}.
__global__ __launch_bounds__(512) void attn_kernel(const ushort* __restrict__ Q,
                                                   const ushort* __restrict__ K,
                                                   const ushort* __restrict__ Vt,
                                                   ushort* __restrict__ AO) {
  __shared__ ushort Ks[4][64 * 64];   // [buf][key][dchunk, chunk^=(key&7)]
  __shared__ ushort Vs[4][64 * 64];   // [buf][hd][keychunk, chunk^=(hd&7)]

  int wave = threadIdx.x >> 6, lane = threadIdx.x & 63;
  int q5 = lane & 31, hi5 = lane >> 5;
  int bh = blockIdx.x, b = bh >> 4, h = bh & 15;
  int y = blockIdx.y;
  int qt = (y < 4) ? (7 - y) : (y - 4);   // heavy-first, CU-paired
  int qw = qt * 256 + wave * 32;

  const ushort* Kbh = K + (size_t)bh * T_ * HD_;
  const ushort* Vbh = Vt + (size_t)bh * HD_ * T_;

  // Q B-fragments: qf[ks] = Q[qw+q5][ks*16 + hi5*8 + j]
  bf16x8 qf[4];
#pragma unroll
  for (int ks = 0; ks < 4; ++ks)
    qf[ks] = *reinterpret_cast<const bf16x8*>(
        Q + ((size_t)bh * T_ + qw + q5) * HD_ + ks * 16 + hi5 * 8);

  f32x16 ot[2];
  ot[0] = zero16(); ot[1] = zero16();
  float mreg = -1e30f, lreg = 0.0f;

  int srow = lane >> 3;   // 0..7
  int sch = lane & 7;     // 16B chunk within 128B row

  int ntiles = qt * 4 + 4;   // always >= 4 and even

  // Each wave stages 8 K-rows + 8 V-rows (1KB each): 2 gload16 per tile.
#define STAGE(BUF, TILE)                                                        \
  {                                                                             \
    int kt_ = (TILE) << 6;                                                      \
    int row = wave * 8 + srow;                                                  \
    const ushort* gk = Kbh + (size_t)(kt_ + row) * HD_ + ((sch ^ (row & 7)) * 8); \
    gload16(gk, &Ks[BUF][(wave * 8) * 64]);                                     \
    int col = (kt_ + ((sch ^ (row & 7)) + row) * 8) & (T_ - 1);                 \
    const ushort* gv = Vbh + (size_t)row * T_ + col;                            \
    gload16(gv, &Vs[BUF][(wave * 8) * 64]);                                     \
  }

  auto compute_tile = [&](int tile, int buf) {
    int kt = tile << 6;
    if (kt > qw + 31) return;   // wave-uniform causal predicate
    // ---- QK^T swapped: s[g] = S[key = kt+g*32+crow(reg,hi5)][q = qw+q5]
    f32x16 s[2];
#pragma unroll
    for (int g = 0; g < 2; ++g) {
      int krow = g * 32 + q5;
      bf16x8 kf[4];
#pragma unroll
      for (int ks = 0; ks < 4; ++ks)
        kf[ks] = *reinterpret_cast<const bf16x8*>(
            &Ks[buf][krow * 64 + (((2 * ks + hi5) ^ (krow & 7)) * 8)]);
      f32x16 acc = zero16();
      __builtin_amdgcn_s_setprio(1);
#pragma unroll
      for (int ks = 0; ks < 4; ++ks)
        acc = __builtin_amdgcn_mfma_f32_32x32x16_bf16(kf[ks], qf[ks], acc, 0, 0, 0);
      __builtin_amdgcn_s_setprio(0);
      s[g] = acc;
    }
    // ---- causal mask (boundary tiles only)
    if (kt + 63 > qw) {
      int q = qw + q5;
#pragma unroll
      for (int g = 0; g < 2; ++g)
#pragma unroll
        for (int r = 0; r < 16; ++r) {
          int key = kt + g * 32 + (r & 3) + 8 * (r >> 2) + 4 * hi5;
          if (key > q) s[g][r] = -1e30f;
        }
    }
    // ---- online softmax: lane-local tree + one lane^32 combine
    float t8[8];
#pragma unroll
    for (int i = 0; i < 8; ++i)
      t8[i] = fmaxf(fmaxf(s[0][i], s[0][i + 8]), fmaxf(s[1][i], s[1][i + 8]));
    float mx = fmaxf(fmaxf(fmaxf(t8[0], t8[1]), fmaxf(t8[2], t8[3])),
                     fmaxf(fmaxf(t8[4], t8[5]), fmaxf(t8[6], t8[7])));
    mx = fmaxf(mx, __shfl_xor(mx, 32));
    float nm = fmaxf(mreg, mx);
    float alpha = exp2f(mreg - nm);
    mreg = nm;
#pragma unroll
    for (int g = 0; g < 2; ++g)
#pragma unroll
      for (int r = 0; r < 16; ++r)
        s[g][r] = exp2f(s[g][r] - nm);
    float u8[8];
#pragma unroll
    for (int i = 0; i < 8; ++i)
      u8[i] = (s[0][i] + s[0][i + 8]) + (s[1][i] + s[1][i + 8]);
    float rs = ((u8[0] + u8[1]) + (u8[2] + u8[3])) + ((u8[4] + u8[5]) + (u8[6] + u8[7]));
    rs += __shfl_xor(rs, 32);
    lreg = lreg * alpha + rs;
#pragma unroll
    for (int nh = 0; nh < 2; ++nh)
#pragma unroll
      for (int r = 0; r < 16; ++r) ot[nh][r] *= alpha;

    // ---- repack P -> PV B-fragments (in-register, cross-half via shfl)
    bf16x8 pb4[4];
#pragma unroll
    for (int ks = 0; ks < 4; ++ks) {
      int g = ks >> 1;
      int R0 = 2 * (ks & 1), R1 = R0 + 1;
      int a0w0 = cvtpk(s[g][4 * R0 + 0], s[g][4 * R0 + 1]);
      int a0w1 = cvtpk(s[g][4 * R0 + 2], s[g][4 * R0 + 3]);
      int a1w0 = cvtpk(s[g][4 * R1 + 0], s[g][4 * R1 + 1]);
      int a1w1 = cvtpk(s[g][4 * R1 + 2], s[g][4 * R1 + 3]);
      int pA0w0 = __shfl_xor(a0w0, 32);
      int pA0w1 = __shfl_xor(a0w1, 32);
      int pA1w0 = __shfl_xor(a1w0, 32);
      int pA1w1 = __shfl_xor(a1w1, 32);
      int4 w;
      w.x = hi5 ? pA1w0 : a0w0;   // keys base+0,1
      w.y = hi5 ? pA1w1 : a0w1;   // keys base+2,3
      w.z = hi5 ? a1w0 : pA0w0;   // keys base+4,5
      w.w = hi5 ? a1w1 : pA0w1;   // keys base+6,7
      pb4[ks] = *reinterpret_cast<bf16x8*>(&w);
    }
    // ---- PV swapped: ot[nh] += V^T x P, rows hd = nh*32+crow(reg,hi5)
#pragma unroll
    for (int nh = 0; nh < 2; ++nh) {
      int vrow = nh * 32 + q5;
      bf16x8 vf[4];
#pragma unroll
      for (int ks = 0; ks < 4; ++ks)
        vf[ks] = *reinterpret_cast<const bf16x8*>(
            &Vs[buf][vrow * 64 + (((2 * ks + hi5) ^ (vrow & 7)) * 8)]);
      __builtin_amdgcn_s_setprio(1);
#pragma unroll
      for (int ks = 0; ks < 4; ++ks)
        ot[nh] = __builtin_amdgcn_mfma_f32_32x32x16_bf16(vf[ks], pb4[ks], ot[nh], 0, 0, 0);
      __builtin_amdgcn_s_setprio(0);
    }
  };

  STAGE(0, 0);
  STAGE(1, 1);

  int npairs = ntiles >> 1;
  for (int p = 0; p < npairs; ++p) {
    int t0 = 2 * p, t1 = 2 * p + 1;
    // loads for tiles t0,t1 were issued a full pair ago -> wait is ~free
    asm volatile("s_waitcnt vmcnt(0)" ::: "memory");
    __builtin_amdgcn_s_barrier();   // raw barrier (no drain re-insertion)
    {
      int pr0 = t0 + 2, pr1 = t0 + 3;
      int s0 = (pr0 < ntiles) ? pr0 : 0;
      int s1 = (pr1 < ntiles) ? pr1 : 0;
      STAGE(pr0 & 3, s0);   // bufs (t0+2)&3,(t0+3)&3: read in pair p-1, all
      STAGE(pr1 & 3, s1);   // waves are past barrier(p) -> race-free
    }
    compute_tile(t0, t0 & 3);
    compute_tile(t1, t1 & 3);
  }
#undef STAGE

  // epilogue: normalize, write AO[b][t][h][hd]; hd = nh*32 + 8R + 4*hi5 + c
  float inv = 1.0f / lreg;
  int t = qw + q5;
  ushort* aop = AO + ((size_t)(b * T_ + t) * H_ + h) * HD_;
#pragma unroll
  for (int nh = 0; nh < 2; ++nh)
#pragma unroll
    for (int R = 0; R < 4; ++R) {
      ushort4 u;
      u.x = f2b(ot[nh][4 * R + 0] * inv);
      u.y = f2b(ot[nh][4 * R + 1] * inv);
      u.z = f2b(ot[nh][4 * R + 2] * inv);
      u.w = f2b(ot[nh][4 * R + 3] * inv);
      *reinterpret_cast<ushort4*>(aop + nh * 32 + 8 * R + 4 * hi5) = u;
    }
}

// ---------------- Output projection, m97-style gload_lds staging (r14) ------
__global__ __launch_bounds__(256) void proj_kernel(const ushort* __restrict__ A,
                                                   const ushort* __restrict__ Wb,
                                                   const float* __restrict__ bias,
                                                   float* __restrict__ out) {
  __shared__ ushort As[2][128 * 32];
  __shared__ ushort Bs[2][128 * 32];
  int tid = threadIdx.x;
  int wave = tid >> 6, lane = tid & 63;
  int lo = lane & 15, hi = lane >> 4;
  int wr = wave >> 1, wc = wave & 1;
  int m0 = blockIdx.y * 128, n0 = blockIdx.x * 128;

  int srow4 = lane >> 2;     // 0..15 (row within 16-row group)
  int sch4 = lane & 3;       // 16B chunk within 64B row
  int swz = sch4 ^ ((srow4 >> 1) & 3);   // pre-swizzled source chunk

#define PSTAGE(BUF, K0)                                                          \
  {                                                                              \
    _Pragma("unroll")                                                            \
    for (int rep = 0; rep < 2; ++rep) {                                          \
      int row = wave * 32 + rep * 16 + srow4;                                    \
      gload16(A + (size_t)(m0 + row) * E_ + (K0) + swz * 8,                      \
              &As[BUF][(wave * 32 + rep * 16) * 32]);                            \
      gload16(Wb + (size_t)(n0 + row) * E_ + (K0) + swz * 8,                     \
              &Bs[BUF][(wave * 32 + rep * 16) * 32]);                            \
    }                                                                            \
  }

  f32x4 acc[4][4] = {};
  PSTAGE(0, 0);
  asm volatile("s_waitcnt vmcnt(0)" ::: "memory");
  __syncthreads();

  int cur = 0;
  for (int k0 = 0; k0 < E_; k0 += 32) {
    int kpre = (k0 + 32) & (E_ - 1);   // last iter harmlessly re-fetches k=0
    PSTAGE(cur ^ 1, kpre);
    bf16x8 af[4], bfr[4];
#pragma unroll
    for (int i = 0; i < 4; ++i) {
      int row = wr * 64 + i * 16 + lo;
      af[i] = *reinterpret_cast<const bf16x8*>(
          &As[cur][row * 32 + ((hi ^ ((row >> 1) & 3)) * 8)]);
    }
#pragma unroll
    for (int j = 0; j < 4; ++j) {
      int row = wc * 64 + j * 16 + lo;
      bfr[j] = *reinterpret_cast<const bf16x8*>(
          &Bs[cur][row * 32 + ((hi ^ ((row >> 1) & 3)) * 8)]);
    }
    __builtin_amdgcn_s_setprio(1);
#pragma unroll
    for (int i = 0; i < 4; ++i)
#pragma unroll
      for (int j = 0; j < 4; ++j)
        acc[i][j] = __builtin_amdgcn_mfma_f32_16x16x32_bf16(af[i], bfr[j], acc[i][j], 0, 0, 0);
    __builtin_amdgcn_s_setprio(0);
    asm volatile("s_waitcnt vmcnt(0)" ::: "memory");
    __syncthreads();
    cur ^= 1;
  }
#undef PSTAGE

#pragma unroll
  for (int i = 0; i < 4; ++i)
#pragma unroll
    for (int r = 0; r < 4; ++r) {
      int mm = m0 + wr * 64 + i * 16 + hi * 4 + r;
      float* orow = out + (size_t)mm * E_ + n0 + wc * 64;
#pragma unroll
      for (int j = 0; j < 4; ++j)
        orow[j * 16 + lo] = acc[i][j][r] + bias[n0 + wc * 64 + j * 16 + lo];
    }
}

extern "C" void kernel_launch(void* const* d_in, const int* in_sizes, int n_in,
                              void* d_out, int out_size, void* d_ws, size_t ws_size,
                              hipStream_t stream) {
  (void)in_sizes; (void)n_in; (void)out_size; (void)ws_size;
  const float* x  = (const float*)d_in[0];
  const float* Wq = (const float*)d_in[1];
  const float* bq = (const float*)d_in[2];
  const float* Wp = (const float*)d_in[3];
  const float* bp = (const float*)d_in[4];
  float* out = (float*)d_out;

  const size_t NQ = (size_t)B_ * H_ * T_ * HD_;
  ushort* ws = (ushort*)d_ws;
  ushort* Q  = ws;
  ushort* K  = ws + NQ;
  ushort* Vt = ws + 2 * NQ;
  ushort* AO = ws + 3 * NQ;
  ushort* Wb = ws + 4 * NQ;
  ushort* Wt = ws + 4 * NQ + (size_t)E_ * E_;

  cvt_kernel<<<dim3(1792), dim3(256), 0, stream>>>(Wq, Wt, Wp, Wb);
  qkv_kernel<<<dim3(T_ / 64, B_ * H_), dim3(256), 0, stream>>>(x, Wt, bq, Q, K, Vt);
  attn_kernel<<<dim3(B_ * H_, 8), dim3(512), 0, stream>>>(Q, K, Vt, AO);
  proj_kernel<<<dim3(E_ / 128, (B_ * T_) / 128), dim3(256), 0, stream>>>(AO, Wb, bp, out);
}

// Round 22
// 140.356 us; speedup vs baseline: 1.1081x; 1.0341x over previous
//
#include <hip/hip_runtime.h>
#include <hip/hip_bf16.h>

#define B_ 4
#define T_ 2048
#define E_ 1024
#define H_ 16
#define HD_ 64

typedef __attribute__((ext_vector_type(8))) short bf16x8;
typedef __attribute__((ext_vector_type(4))) float f32x4;
typedef __attribute__((ext_vector_type(16))) float f32x16;

__device__ inline ushort f2b(float f) {
  union { __hip_bfloat16 h; ushort u; } c;
  c.h = __float2bfloat16(f);
  return c.u;
}
__device__ inline short f2bs(float f) {
  union { __hip_bfloat16 h; short s; } c;
  c.h = __float2bfloat16(f);
  return c.s;
}
__device__ inline int cvtpk(float lo, float hi) {
  int r;
  asm("v_cvt_pk_bf16_f32 %0, %1, %2" : "=v"(r) : "v"(lo), "v"(hi));
  return r;
}
__device__ inline f32x16 zero16() {
  f32x16 z;
#pragma unroll
  for (int i = 0; i < 16; ++i) z[i] = 0.0f;
  return z;
}

// async global->LDS, 16B per lane; lds base must be wave-uniform
__device__ inline void gload16(const ushort* gsrc, ushort* lds_uniform_base) {
  __builtin_amdgcn_global_load_lds(
      (const __attribute__((address_space(1))) void*)gsrc,
      (__attribute__((address_space(3))) void*)lds_uniform_base, 16, 0, 0);
}

// ---------------- merged weight conversion (r18) -----------------------------
__global__ __launch_bounds__(256) void cvt_kernel(const float* __restrict__ Wq,
                                                  ushort* __restrict__ Wt,
                                                  const float* __restrict__ Wp,
                                                  ushort* __restrict__ Wb) {
  int bid = blockIdx.x;
  if (bid < 768) {
    int gtid = bid * 256 + threadIdx.x;   // 0 .. 196607
    int h = gtid / (HD_ * 192);
    int rem = gtid % (HD_ * 192);
    int d = rem / 192;
    int e = rem % 192;
    int v = (e >> 6) * 64 + (e & 3) * 16 + ((e >> 2) & 15);
    Wt[h * (192 * HD_) + v * HD_ + d] = f2b(Wq[gtid]);
  } else {
    int i = ((bid - 768) * 256 + threadIdx.x) * 4;
    float4 f = *reinterpret_cast<const float4*>(Wp + i);
    ushort4 u;
    u.x = f2b(f.x); u.y = f2b(f.y); u.z = f2b(f.z); u.w = f2b(f.w);
    *reinterpret_cast<ushort4*>(Wb + i) = u;
  }
}

// ---------------- QKV projection (r18) ---------------------------------------
__global__ __launch_bounds__(256) void qkv_kernel(const float* __restrict__ x,
                                                  const ushort* __restrict__ Wt,
                                                  const float* __restrict__ bq,
                                                  ushort* __restrict__ Q,
                                                  ushort* __restrict__ K,
                                                  ushort* __restrict__ Vt) {
  const float SCALE = (1.0f / (8.0f + 1e-5f)) * 1.4426950408889634f;
  int wave = threadIdx.x >> 6, lane = threadIdx.x & 63;
  int lo = lane & 15, hi = lane >> 4;
  int bh = blockIdx.y, b = bh >> 4, h = bh & 15;
  int t0 = blockIdx.x * 64 + wave * 16;

  const float* xr = x + (size_t)(b * T_ + t0 + lo) * E_ + h * HD_;
  bf16x8 af[2];
#pragma unroll
  for (int c = 0; c < 2; ++c) {
    float4 f0 = *reinterpret_cast<const float4*>(xr + c * 32 + hi * 8);
    float4 f1 = *reinterpret_cast<const float4*>(xr + c * 32 + hi * 8 + 4);
    bf16x8 v;
    v[0] = f2bs(f0.x); v[1] = f2bs(f0.y); v[2] = f2bs(f0.z); v[3] = f2bs(f0.w);
    v[4] = f2bs(f1.x); v[5] = f2bs(f1.y); v[6] = f2bs(f1.z); v[7] = f2bs(f1.w);
    af[c] = v;
  }

  const ushort* Wh = Wt + h * (192 * HD_);
#pragma unroll
  for (int g = 0; g < 3; ++g) {          // 0=Q, 1=K, 2=V
    f32x4 accg[4];
#pragma unroll
    for (int j = 0; j < 4; ++j) {
      int n0 = (g * 4 + j) * 16;
      bf16x8 bf0 = *reinterpret_cast<const bf16x8*>(Wh + (size_t)(n0 + lo) * HD_ + hi * 8);
      bf16x8 bf1 = *reinterpret_cast<const bf16x8*>(Wh + (size_t)(n0 + lo) * HD_ + 32 + hi * 8);
      f32x4 acc = {0.0f, 0.0f, 0.0f, 0.0f};
      acc = __builtin_amdgcn_mfma_f32_16x16x32_bf16(af[0], bf0, acc, 0, 0, 0);
      acc = __builtin_amdgcn_mfma_f32_16x16x32_bf16(af[1], bf1, acc, 0, 0, 0);
      accg[j] = acc;
    }
    float4 bq4 = *reinterpret_cast<const float4*>(bq + h * 192 + g * 64 + 4 * lo);
    if (g < 2) {
      ushort* dst = (g == 0) ? Q : K;
      float sc = (g == 0) ? SCALE : 1.0f;
#pragma unroll
      for (int r = 0; r < 4; ++r) {
        int t = t0 + hi * 4 + r;
        ushort4 u;
        u.x = f2b((accg[0][r] + bq4.x) * sc);
        u.y = f2b((accg[1][r] + bq4.y) * sc);
        u.z = f2b((accg[2][r] + bq4.z) * sc);
        u.w = f2b((accg[3][r] + bq4.w) * sc);
        *reinterpret_cast<ushort4*>(dst + ((size_t)bh * T_ + t) * HD_ + 4 * lo) = u;
      }
    } else {
      float bj[4] = {bq4.x, bq4.y, bq4.z, bq4.w};
#pragma unroll
      for (int j = 0; j < 4; ++j) {
        int hd = 4 * lo + j;
        ushort4 u;
        u.x = f2b(accg[j][0] + bj[j]);
        u.y = f2b(accg[j][1] + bj[j]);
        u.z = f2b(accg[j][2] + bj[j]);
        u.w = f2b(accg[j][3] + bj[j]);
        int col = t0 + hi * 4 + hd * 8;
        col &= (T_ - 1);
        *reinterpret_cast<ushort4*>(Vt + ((size_t)bh * HD_ + hd) * T_ + col) = u;
      }
    }
  }
}

// ---------------- Flash attention (causal), swapped-operand 32x32 (r15) -----
__global__ __launch_bounds__(512) void attn_kernel(const ushort* __restrict__ Q,
                                                   const ushort* __restrict__ K,
                                                   const ushort* __restrict__ Vt,
                                                   ushort* __restrict__ AO) {
  __shared__ ushort Ks[4][64 * 64];   // [buf][key][dchunk, chunk^=(key&7)]
  __shared__ ushort Vs[4][64 * 64];   // [buf][hd][keychunk, chunk^=(hd&7)]

  int wave = threadIdx.x >> 6, lane = threadIdx.x & 63;
  int q5 = lane & 31, hi5 = lane >> 5;
  int bh = blockIdx.x, b = bh >> 4, h = bh & 15;
  int y = blockIdx.y;
  int qt = (y < 4) ? (7 - y) : (y - 4);   // heavy-first, CU-paired
  int qw = qt * 256 + wave * 32;

  const ushort* Kbh = K + (size_t)bh * T_ * HD_;
  const ushort* Vbh = Vt + (size_t)bh * HD_ * T_;

  bf16x8 qf[4];
#pragma unroll
  for (int ks = 0; ks < 4; ++ks)
    qf[ks] = *reinterpret_cast<const bf16x8*>(
        Q + ((size_t)bh * T_ + qw + q5) * HD_ + ks * 16 + hi5 * 8);

  f32x16 ot[2];
  ot[0] = zero16(); ot[1] = zero16();
  float mreg = -1e30f, lreg = 0.0f;

  int srow = lane >> 3;   // 0..7
  int sch = lane & 7;     // 16B chunk within 128B row

  int ntiles = qt * 4 + 4;   // always >= 4 and even

#define STAGE(BUF, TILE)                                                        \
  {                                                                             \
    int kt_ = (TILE) << 6;                                                      \
    int row = wave * 8 + srow;                                                  \
    const ushort* gk = Kbh + (size_t)(kt_ + row) * HD_ + ((sch ^ (row & 7)) * 8); \
    gload16(gk, &Ks[BUF][(wave * 8) * 64]);                                     \
    int col = (kt_ + ((sch ^ (row & 7)) + row) * 8) & (T_ - 1);                 \
    const ushort* gv = Vbh + (size_t)row * T_ + col;                            \
    gload16(gv, &Vs[BUF][(wave * 8) * 64]);                                     \
  }

  auto compute_tile = [&](int tile, int buf) {
    int kt = tile << 6;
    if (kt > qw + 31) return;   // wave-uniform causal predicate
    f32x16 s[2];
#pragma unroll
    for (int g = 0; g < 2; ++g) {
      int krow = g * 32 + q5;
      bf16x8 kf[4];
#pragma unroll
      for (int ks = 0; ks < 4; ++ks)
        kf[ks] = *reinterpret_cast<const bf16x8*>(
            &Ks[buf][krow * 64 + (((2 * ks + hi5) ^ (krow & 7)) * 8)]);
      f32x16 acc = zero16();
      __builtin_amdgcn_s_setprio(1);
#pragma unroll
      for (int ks = 0; ks < 4; ++ks)
        acc = __builtin_amdgcn_mfma_f32_32x32x16_bf16(kf[ks], qf[ks], acc, 0, 0, 0);
      __builtin_amdgcn_s_setprio(0);
      s[g] = acc;
    }
    if (kt + 63 > qw) {
      int q = qw + q5;
#pragma unroll
      for (int g = 0; g < 2; ++g)
#pragma unroll
        for (int r = 0; r < 16; ++r) {
          int key = kt + g * 32 + (r & 3) + 8 * (r >> 2) + 4 * hi5;
          if (key > q) s[g][r] = -1e30f;
        }
    }
    float t8[8];
#pragma unroll
    for (int i = 0; i < 8; ++i)
      t8[i] = fmaxf(fmaxf(s[0][i], s[0][i + 8]), fmaxf(s[1][i], s[1][i + 8]));
    float mx = fmaxf(fmaxf(fmaxf(t8[0], t8[1]), fmaxf(t8[2], t8[3])),
                     fmaxf(fmaxf(t8[4], t8[5]), fmaxf(t8[6], t8[7])));
    mx = fmaxf(mx, __shfl_xor(mx, 32));
    float nm = fmaxf(mreg, mx);
    float alpha = exp2f(mreg - nm);
    mreg = nm;
#pragma unroll
    for (int g = 0; g < 2; ++g)
#pragma unroll
      for (int r = 0; r < 16; ++r)
        s[g][r] = exp2f(s[g][r] - nm);
    float u8[8];
#pragma unroll
    for (int i = 0; i < 8; ++i)
      u8[i] = (s[0][i] + s[0][i + 8]) + (s[1][i] + s[1][i + 8]);
    float rs = ((u8[0] + u8[1]) + (u8[2] + u8[3])) + ((u8[4] + u8[5]) + (u8[6] + u8[7]));
    rs += __shfl_xor(rs, 32);
    lreg = lreg * alpha + rs;
#pragma unroll
    for (int nh = 0; nh < 2; ++nh)
#pragma unroll
      for (int r = 0; r < 16; ++r) ot[nh][r] *= alpha;

    bf16x8 pb4[4];
#pragma unroll
    for (int ks = 0; ks < 4; ++ks) {
      int g = ks >> 1;
      int R0 = 2 * (ks & 1), R1 = R0 + 1;
      int a0w0 = cvtpk(s[g][4 * R0 + 0], s[g][4 * R0 + 1]);
      int a0w1 = cvtpk(s[g][4 * R0 + 2], s[g][4 * R0 + 3]);
      int a1w0 = cvtpk(s[g][4 * R1 + 0], s[g][4 * R1 + 1]);
      int a1w1 = cvtpk(s[g][4 * R1 + 2], s[g][4 * R1 + 3]);
      int pA0w0 = __shfl_xor(a0w0, 32);
      int pA0w1 = __shfl_xor(a0w1, 32);
      int pA1w0 = __shfl_xor(a1w0, 32);
      int pA1w1 = __shfl_xor(a1w1, 32);
      int4 w;
      w.x = hi5 ? pA1w0 : a0w0;   // keys base+0,1
      w.y = hi5 ? pA1w1 : a0w1;   // keys base+2,3
      w.z = hi5 ? a1w0 : pA0w0;   // keys base+4,5
      w.w = hi5 ? a1w1 : pA0w1;   // keys base+6,7
      pb4[ks] = *reinterpret_cast<bf16x8*>(&w);
    }
#pragma unroll
    for (int nh = 0; nh < 2; ++nh) {
      int vrow = nh * 32 + q5;
      bf16x8 vf[4];
#pragma unroll
      for (int ks = 0; ks < 4; ++ks)
        vf[ks] = *reinterpret_cast<const bf16x8*>(
            &Vs[buf][vrow * 64 + (((2 * ks + hi5) ^ (vrow & 7)) * 8)]);
      __builtin_amdgcn_s_setprio(1);
#pragma unroll
      for (int ks = 0; ks < 4; ++ks)
        ot[nh] = __builtin_amdgcn_mfma_f32_32x32x16_bf16(vf[ks], pb4[ks], ot[nh], 0, 0, 0);
      __builtin_amdgcn_s_setprio(0);
    }
  };

  STAGE(0, 0);
  STAGE(1, 1);

  int npairs = ntiles >> 1;
  for (int p = 0; p < npairs; ++p) {
    int t0 = 2 * p, t1 = 2 * p + 1;
    asm volatile("s_waitcnt vmcnt(0)" ::: "memory");
    __builtin_amdgcn_s_barrier();   // raw barrier (no drain re-insertion)
    {
      int pr0 = t0 + 2, pr1 = t0 + 3;
      int s0 = (pr0 < ntiles) ? pr0 : 0;
      int s1 = (pr1 < ntiles) ? pr1 : 0;
      STAGE(pr0 & 3, s0);
      STAGE(pr1 & 3, s1);
    }
    compute_tile(t0, t0 & 3);
    compute_tile(t1, t1 & 3);
  }
#undef STAGE

  float inv = 1.0f / lreg;
  int t = qw + q5;
  ushort* aop = AO + ((size_t)(b * T_ + t) * H_ + h) * HD_;
#pragma unroll
  for (int nh = 0; nh < 2; ++nh)
#pragma unroll
    for (int R = 0; R < 4; ++R) {
      ushort4 u;
      u.x = f2b(ot[nh][4 * R + 0] * inv);
      u.y = f2b(ot[nh][4 * R + 1] * inv);
      u.z = f2b(ot[nh][4 * R + 2] * inv);
      u.w = f2b(ot[nh][4 * R + 3] * inv);
      *reinterpret_cast<ushort4*>(aop + nh * 32 + 8 * R + 4 * hi5) = u;
    }
}

// ---------------- Output projection, BK=64 gload_lds staging ------------------
// [8192,1024] x [1024,1024]^T + bias. 128x128 tile, BK=64 (16 K-steps, half
// the sync events of BK=32), 4 waves (2x2), each wave 64x64.
// LDS [128][64] per buffer, 128B rows; lane map: 8 rows/instr (lane>>3),
// chunk lane&7; bank swizzle chunk^=(row&7) on BOTH sides (2-way = free).
__global__ __launch_bounds__(256) void proj_kernel(const ushort* __restrict__ A,
                                                   const ushort* __restrict__ Wb,
                                                   const float* __restrict__ bias,
                                                   float* __restrict__ out) {
  __shared__ ushort As[2][128 * 64];
  __shared__ ushort Bs[2][128 * 64];
  int tid = threadIdx.x;
  int wave = tid >> 6, lane = tid & 63;
  int lo = lane & 15, hi = lane >> 4;
  int wr = wave >> 1, wc = wave & 1;
  int m0 = blockIdx.y * 128, n0 = blockIdx.x * 128;

  int srow8 = lane >> 3;     // 0..7 (row within 8-row group)
  int sch8 = lane & 7;       // 16B chunk within 128B row
  int swz = sch8 ^ srow8;    // pre-swizzled source chunk (row&7 == srow8)

#define PSTAGE(BUF, K0)                                                          \
  {                                                                              \
    _Pragma("unroll")                                                            \
    for (int rep = 0; rep < 4; ++rep) {                                          \
      int row = wave * 32 + rep * 8 + srow8;                                     \
      gload16(A + (size_t)(m0 + row) * E_ + (K0) + swz * 8,                      \
              &As[BUF][(wave * 32 + rep * 8) * 64]);                             \
      gload16(Wb + (size_t)(n0 + row) * E_ + (K0) + swz * 8,                     \
              &Bs[BUF][(wave * 32 + rep * 8) * 64]);                             \
    }                                                                            \
  }

  f32x4 acc[4][4] = {};
  PSTAGE(0, 0);
  asm volatile("s_waitcnt vmcnt(0)" ::: "memory");
  __syncthreads();

  int cur = 0;
  for (int k0 = 0; k0 < E_; k0 += 64) {
    int kpre = (k0 + 64) & (E_ - 1);   // last iter harmlessly re-fetches k=0
    PSTAGE(cur ^ 1, kpre);
#pragma unroll
    for (int hh = 0; hh < 2; ++hh) {   // two K=32 sub-tiles of the 64-col buf
      bf16x8 af[4], bfr[4];
#pragma unroll
      for (int i = 0; i < 4; ++i) {
        int row = wr * 64 + i * 16 + lo;
        af[i] = *reinterpret_cast<const bf16x8*>(
            &As[cur][row * 64 + (((hh * 4 + hi) ^ (row & 7)) * 8)]);
      }
#pragma unroll
      for (int j = 0; j < 4; ++j) {
        int row = wc * 64 + j * 16 + lo;
        bfr[j] = *reinterpret_cast<const bf16x8*>(
            &Bs[cur][row * 64 + (((hh * 4 + hi) ^ (row & 7)) * 8)]);
      }
      __builtin_amdgcn_s_setprio(1);
#pragma unroll
      for (int i = 0; i < 4; ++i)
#pragma unroll
        for (int j = 0; j < 4; ++j)
          acc[i][j] = __builtin_amdgcn_mfma_f32_16x16x32_bf16(af[i], bfr[j], acc[i][j], 0, 0, 0);
      __builtin_amdgcn_s_setprio(0);
    }
    asm volatile("s_waitcnt vmcnt(0)" ::: "memory");
    __syncthreads();
    cur ^= 1;
  }
#undef PSTAGE

#pragma unroll
  for (int i = 0; i < 4; ++i)
#pragma unroll
    for (int r = 0; r < 4; ++r) {
      int mm = m0 + wr * 64 + i * 16 + hi * 4 + r;
      float* orow = out + (size_t)mm * E_ + n0 + wc * 64;
#pragma unroll
      for (int j = 0; j < 4; ++j)
        orow[j * 16 + lo] = acc[i][j][r] + bias[n0 + wc * 64 + j * 16 + lo];
    }
}

extern "C" void kernel_launch(void* const* d_in, const int* in_sizes, int n_in,
                              void* d_out, int out_size, void* d_ws, size_t ws_size,
                              hipStream_t stream) {
  (void)in_sizes; (void)n_in; (void)out_size; (void)ws_size;
  const float* x  = (const float*)d_in[0];
  const float* Wq = (const float*)d_in[1];
  const float* bq = (const float*)d_in[2];
  const float* Wp = (const float*)d_in[3];
  const float* bp = (const float*)d_in[4];
  float* out = (float*)d_out;

  const size_t NQ = (size_t)B_ * H_ * T_ * HD_;
  ushort* ws = (ushort*)d_ws;
  ushort* Q  = ws;
  ushort* K  = ws + NQ;
  ushort* Vt = ws + 2 * NQ;
  ushort* AO = ws + 3 * NQ;
  ushort* Wb = ws + 4 * NQ;
  ushort* Wt = ws + 4 * NQ + (size_t)E_ * E_;

  cvt_kernel<<<dim3(1792), dim3(256), 0, stream>>>(Wq, Wt, Wp, Wb);
  qkv_kernel<<<dim3(T_ / 64, B_ * H_), dim3(256), 0, stream>>>(x, Wt, bq, Q, K, Vt);
  attn_kernel<<<dim3(B_ * H_, 8), dim3(512), 0, stream>>>(Q, K, Vt, AO);
  proj_kernel<<<dim3(E_ / 128, (B_ * T_) / 128), dim3(256), 0, stream>>>(AO, Wb, bp, out);
}